// Round 2
// baseline (759.080 us; speedup 1.0000x reference)
//
#include <hip/hip_runtime.h>
#include <math.h>

#define N_NODES 100000
#define N_EDGES 1600000
#define SF_DIM  80   // 16 edge feats + 64 node feats
#define OUT_F   64

// ---------------------------------------------------------------------------
// CSR build, step 1: degree histogram. 1.6M u32 atomics into 400 KB (L2-able)
// ---------------------------------------------------------------------------
__global__ __launch_bounds__(256) void hist_kernel(
    const int* __restrict__ dst, unsigned* __restrict__ deg_i)
{
    int e = blockIdx.x * 256 + threadIdx.x;
    if (e < N_EDGES) atomicAdd(&deg_i[dst[e]], 1u);
}

// ---------------------------------------------------------------------------
// CSR build, step 2: exclusive scan of 100k degrees. Single 1024-thread block:
// serial per-thread partials (98 elems) -> LDS scan of 1024 -> serial emit.
// ~25 barriers total.
// ---------------------------------------------------------------------------
__global__ __launch_bounds__(1024) void scan_kernel(
    const unsigned* __restrict__ deg_i, unsigned* __restrict__ off)
{
    __shared__ unsigned sums[1024];
    int tid = threadIdx.x;
    const int CH = (N_NODES + 1023) / 1024;   // 98
    int s = tid * CH;
    int e = min(s + CH, N_NODES);
    unsigned local = 0;
    for (int i = s; i < e; ++i) local += deg_i[i];
    sums[tid] = local;
    __syncthreads();
    #pragma unroll
    for (int ofs = 1; ofs < 1024; ofs <<= 1) {
        unsigned t = (tid >= ofs) ? sums[tid - ofs] : 0u;
        __syncthreads();
        sums[tid] += t;
        __syncthreads();
    }
    unsigned run = sums[tid] - local;   // exclusive prefix for this segment
    for (int i = s; i < e; ++i) { off[i] = run; run += deg_i[i]; }
    if (tid == 1023) off[N_NODES] = run;   // == N_EDGES
}

// ---------------------------------------------------------------------------
// CSR build, step 3: counting-sort fill. One packed 8B store per edge:
// low 32 = src node, high 32 = edge id. 1.6M cursor atomics (L2-resident).
// ---------------------------------------------------------------------------
__global__ __launch_bounds__(256) void fill_kernel(
    const int* __restrict__ src, const int* __restrict__ dst,
    const unsigned* __restrict__ off, unsigned* __restrict__ cursor,
    unsigned long long* __restrict__ csr_pack)
{
    int e = blockIdx.x * 256 + threadIdx.x;
    if (e >= N_EDGES) return;
    int d = dst[e];
    unsigned pos = atomicAdd(&cursor[d], 1u);
    unsigned idx = off[d] + pos;
    csr_pack[idx] = (unsigned long long)(unsigned)src[e]
                  | ((unsigned long long)(unsigned)e << 32);
}

// ---------------------------------------------------------------------------
// Fused gather + normalize + 80x64 GEMM + bias + SELU. One wave per node.
//  - sum_h: per edge, 64 lanes read feat[s][0:64] — one fully-used 256 B row
//  - sum_e: 4 edges/iter, lane = (edge group g, feature f) — 64 B rows
//  - group-reduce sum_e via shfl_down(32/16), stage sf row in LDS, dot with
//    W (20 KB LDS), epilogue in-register. sum_f never hits global memory.
// ---------------------------------------------------------------------------
__global__ __launch_bounds__(256) void gather_gemm(
    const float* __restrict__ feat,
    const float* __restrict__ edge_feats,
    const unsigned long long* __restrict__ csr_pack,
    const unsigned* __restrict__ off,
    const float* __restrict__ weight,   // [80][64]
    const float* __restrict__ bias,     // [64]
    float* __restrict__ out)            // [N_NODES][64]
{
    __shared__ float Wl[SF_DIM * OUT_F];   // 20 KB
    __shared__ float sf[4][SF_DIM];

    int tid = threadIdx.x;
    for (int i = tid; i < SF_DIM * OUT_F; i += 256) Wl[i] = weight[i];
    __syncthreads();

    int wv = tid >> 6;
    int ln = tid & 63;
    int g  = ln >> 4;      // edge group 0..3 for the edge-feat loop
    int f  = ln & 15;      // edge feature 0..15
    float b = bias[ln];

    const float SC = 1.0507009873554805f;   // selu scale
    const float AL = 1.6732632423543772f;   // selu alpha

    int n = blockIdx.x * 4 + wv;
    if (n >= N_NODES) return;

    unsigned start = off[n], end = off[n + 1];
    float degf = (float)(end - start);
    float nrm = rsqrtf(fmaxf(degf, 1.0f));

    // --- sum_h: lane ln accumulates feat[s][ln] over the segment ---
    float acc_h = 0.f;
    for (unsigned p = start; p < end; ++p) {
        unsigned long long pk = csr_pack[p];          // wave-broadcast read
        unsigned s = (unsigned)pk;
        acc_h += feat[(size_t)s * 64u + (unsigned)ln];
    }

    // --- sum_e: 4 edges per iteration, 16 features per edge ---
    float acc_e = 0.f;
    for (unsigned p = start + (unsigned)g; p < end; p += 4u) {
        unsigned long long pk = csr_pack[p];
        unsigned eid = (unsigned)(pk >> 32);
        acc_e += edge_feats[(size_t)eid * 16u + (unsigned)f];
    }
    // reduce the 4 groups down to lanes 0..15
    acc_e += __shfl_down(acc_e, 32);
    acc_e += __shfl_down(acc_e, 16);

    // --- stage normalized sf row [e(16) | h(64)] in this wave's LDS slot ---
    sf[wv][16 + ln] = acc_h * nrm;
    if (ln < 16) sf[wv][ln] = acc_e * nrm;
    // same-wave LDS write->read ordered by lgkmcnt (validated round 1)

    float acc = 0.f;
    #pragma unroll
    for (int k = 0; k < SF_DIM; ++k)
        acc = fmaf(sf[wv][k], Wl[k * OUT_F + ln], acc);

    float o = acc * nrm + b;
    out[(size_t)n * OUT_F + ln] = (o > 0.f) ? SC * o : SC * AL * expm1f(o);
}

extern "C" void kernel_launch(void* const* d_in, const int* in_sizes, int n_in,
                              void* d_out, int out_size, void* d_ws, size_t ws_size,
                              hipStream_t stream) {
    const float* feat       = (const float*)d_in[0];
    const float* edge_feats = (const float*)d_in[1];
    const int*   src        = (const int*)d_in[2];
    const int*   dst        = (const int*)d_in[3];
    const float* weight     = (const float*)d_in[4];
    const float* bias       = (const float*)d_in[5];
    float* out = (float*)d_out;

    // workspace layout (8B-aligned head): csr_pack | deg_i | cursor | off
    unsigned long long* csr_pack = (unsigned long long*)d_ws;          // 12.8 MB
    unsigned* deg_i  = (unsigned*)(csr_pack + N_EDGES);                // 400 KB
    unsigned* cursor = deg_i + N_NODES;                                // 400 KB
    unsigned* off    = cursor + N_NODES;                               // 400 KB + 4

    // zero deg_i + cursor in one shot (adjacent)
    hipMemsetAsync(deg_i, 0, 2u * N_NODES * sizeof(unsigned), stream);

    hist_kernel<<<dim3((N_EDGES + 255) / 256), dim3(256), 0, stream>>>(dst, deg_i);
    scan_kernel<<<dim3(1), dim3(1024), 0, stream>>>(deg_i, off);
    fill_kernel<<<dim3((N_EDGES + 255) / 256), dim3(256), 0, stream>>>(
        src, dst, off, cursor, csr_pack);
    gather_gemm<<<dim3((N_NODES + 3) / 4), dim3(256), 0, stream>>>(
        feat, edge_feats, csr_pack, off, weight, bias, out);
}

// Round 3
// 529.219 us; speedup vs baseline: 1.4343x; 1.4343x over previous
//
#include <hip/hip_runtime.h>
#include <math.h>

#define N_NODES 100000
#define N_EDGES 1600000
#define SF_DIM  80   // 16 edge feats + 64 node feats
#define OUT_F   64
#define SCAN_B  1024
#define NBLK    ((N_NODES + SCAN_B - 1) / SCAN_B)   // 98

// ---------------------------------------------------------------------------
// CSR build 1: degree histogram. 1.6M u32 atomics into 400 KB (L2-resident).
// ---------------------------------------------------------------------------
__global__ __launch_bounds__(256) void hist_kernel(
    const int* __restrict__ dst, unsigned* __restrict__ deg_i)
{
    int e = blockIdx.x * 256 + threadIdx.x;
    if (e < N_EDGES) atomicAdd(&deg_i[dst[e]], 1u);
}

// ---------------------------------------------------------------------------
// CSR build 2a: per-block (1024 nodes) degree sum. All CUs busy.
// ---------------------------------------------------------------------------
__global__ __launch_bounds__(SCAN_B) void scanA(
    const unsigned* __restrict__ deg_i, unsigned* __restrict__ bsum)
{
    __shared__ unsigned ws[16];
    int i = blockIdx.x * SCAN_B + threadIdx.x;
    unsigned v = (i < N_NODES) ? deg_i[i] : 0u;
    #pragma unroll
    for (int o = 32; o; o >>= 1) v += __shfl_down(v, o);
    if ((threadIdx.x & 63) == 0) ws[threadIdx.x >> 6] = v;
    __syncthreads();
    if (threadIdx.x < 16) {
        unsigned t = ws[threadIdx.x];
        #pragma unroll
        for (int o = 8; o; o >>= 1) t += __shfl_down(t, o);
        if (threadIdx.x == 0) bsum[blockIdx.x] = t;
    }
}

// ---------------------------------------------------------------------------
// CSR build 2b: exclusive scan of the 98 block sums. One tiny block.
// ---------------------------------------------------------------------------
__global__ __launch_bounds__(128) void scanB(
    const unsigned* __restrict__ bsum, unsigned* __restrict__ boff)
{
    __shared__ unsigned s[128];
    int t = threadIdx.x;
    unsigned v = (t < NBLK) ? bsum[t] : 0u;
    s[t] = v; __syncthreads();
    #pragma unroll
    for (int o = 1; o < 128; o <<= 1) {
        unsigned u = (t >= o) ? s[t - o] : 0u;
        __syncthreads();
        s[t] += u;
        __syncthreads();
    }
    if (t < NBLK) boff[t] = s[t] - v;   // exclusive
}

// ---------------------------------------------------------------------------
// CSR build 2c: per-block exclusive scan + block offset -> off[] AND cursor[]
// (cursor starts at off so fill's atomicAdd returns the absolute slot).
// ---------------------------------------------------------------------------
__global__ __launch_bounds__(SCAN_B) void scanC(
    const unsigned* __restrict__ deg_i, const unsigned* __restrict__ boff,
    unsigned* __restrict__ off, unsigned* __restrict__ cursor)
{
    __shared__ unsigned s[SCAN_B];
    int t = threadIdx.x;
    int i = blockIdx.x * SCAN_B + t;
    unsigned v = (i < N_NODES) ? deg_i[i] : 0u;
    s[t] = v; __syncthreads();
    #pragma unroll
    for (int o = 1; o < SCAN_B; o <<= 1) {
        unsigned u = (t >= o) ? s[t - o] : 0u;
        __syncthreads();
        s[t] += u;
        __syncthreads();
    }
    unsigned excl = s[t] - v + boff[blockIdx.x];
    if (i < N_NODES) { off[i] = excl; cursor[i] = excl; }
    if (i == N_NODES - 1) off[N_NODES] = excl + v;
}

// ---------------------------------------------------------------------------
// CSR build 3: counting-sort fill. cursor pre-seeded with off, so one atomic
// gives the absolute slot. One packed 8B store per edge (src | eid<<32).
// ---------------------------------------------------------------------------
__global__ __launch_bounds__(256) void fill_kernel(
    const int* __restrict__ src, const int* __restrict__ dst,
    unsigned* __restrict__ cursor, unsigned long long* __restrict__ csr_pack)
{
    int e = blockIdx.x * 256 + threadIdx.x;
    if (e >= N_EDGES) return;
    unsigned idx = atomicAdd(&cursor[dst[e]], 1u);
    csr_pack[idx] = (unsigned long long)(unsigned)src[e]
                  | ((unsigned long long)(unsigned)e << 32);
}

// ---------------------------------------------------------------------------
// Fused gather + normalize + 80x64 GEMM + bias + SELU. One wave per node,
// persistent blocks (W staged once per block).
// Latency fix vs round 2: per 64-edge chunk, each lane pre-loads one packed
// CSR entry (coalesced 512 B), then src/eid are broadcast via __shfl — the
// 5 loads per 4-edge group (4 feat rows + 1 edge_feats row across lanes) are
// all INDEPENDENT, giving ~5 outstanding requests instead of a serial
// pk->feat dependent chain.
// ---------------------------------------------------------------------------
__global__ __launch_bounds__(256) void gather_gemm(
    const float* __restrict__ feat,
    const float* __restrict__ edge_feats,
    const unsigned long long* __restrict__ csr_pack,
    const unsigned* __restrict__ off,
    const float* __restrict__ weight,   // [80][64]
    const float* __restrict__ bias,     // [64]
    float* __restrict__ out)            // [N_NODES][64]
{
    __shared__ float Wl[SF_DIM * OUT_F];   // 20 KB
    __shared__ float sf[4][SF_DIM];

    int tid = threadIdx.x;
    for (int i = tid; i < SF_DIM * OUT_F; i += 256) Wl[i] = weight[i];
    __syncthreads();

    int wv = tid >> 6;
    int ln = tid & 63;
    int g  = ln >> 4;      // edge group 0..3
    int f  = ln & 15;      // edge feature 0..15
    float b = bias[ln];

    const float SC = 1.0507009873554805f;
    const float AL = 1.6732632423543772f;

    for (int n = blockIdx.x * 4 + wv; n < N_NODES; n += gridDim.x * 4) {
        unsigned start = off[n], end = off[n + 1];
        float nrm = rsqrtf(fmaxf((float)(end - start), 1.0f));

        float acc_h0 = 0.f, acc_h1 = 0.f, acc_e = 0.f;

        for (unsigned base = start; base < end; base += 64u) {
            unsigned m = min(64u, end - base);
            unsigned lo = 0u, hi = 0u;
            if ((unsigned)ln < m) {
                unsigned long long pk = csr_pack[base + (unsigned)ln];
                lo = (unsigned)pk;
                hi = (unsigned)(pk >> 32);
            }
            unsigned i = 0;
            for (; i + 4u <= m; i += 4u) {
                unsigned s0 = __shfl(lo, (int)i);
                unsigned s1 = __shfl(lo, (int)i + 1);
                unsigned s2 = __shfl(lo, (int)i + 2);
                unsigned s3 = __shfl(lo, (int)i + 3);
                unsigned eg = __shfl(hi, (int)i + g);
                float ef = edge_feats[(size_t)eg * 16u + (unsigned)f];
                float h0 = feat[(size_t)s0 * 64u + (unsigned)ln];
                float h1 = feat[(size_t)s1 * 64u + (unsigned)ln];
                float h2 = feat[(size_t)s2 * 64u + (unsigned)ln];
                float h3 = feat[(size_t)s3 * 64u + (unsigned)ln];
                acc_e  += ef;
                acc_h0 += h0; acc_h1 += h1;
                acc_h0 += h2; acc_h1 += h3;
            }
            for (; i < m; ++i) {
                unsigned si = __shfl(lo, (int)i);
                unsigned ei = __shfl(hi, (int)i);
                acc_h0 += feat[(size_t)si * 64u + (unsigned)ln];
                if (ln < 16) acc_e += edge_feats[(size_t)ei * 16u + (unsigned)ln];
            }
        }
        float acc_h = acc_h0 + acc_h1;

        // fold the 4 edge groups onto lanes 0..15 (feature = ln)
        acc_e += __shfl_down(acc_e, 32);
        acc_e += __shfl_down(acc_e, 16);

        // sf row = [sum_e(16) | sum_h(64)] * nrm, staged in this wave's slot
        sf[wv][16 + ln] = acc_h * nrm;
        if (ln < 16) sf[wv][ln] = acc_e * nrm;
        // same-wave LDS write->read ordered via lgkmcnt (validated R1/R2)

        float a0 = 0.f, a1 = 0.f;
        #pragma unroll
        for (int k = 0; k < SF_DIM; k += 2) {
            a0 = fmaf(sf[wv][k],     Wl[k * OUT_F + ln],       a0);
            a1 = fmaf(sf[wv][k + 1], Wl[(k + 1) * OUT_F + ln], a1);
        }
        float o = (a0 + a1) * nrm + b;
        out[(size_t)n * OUT_F + ln] = (o > 0.f) ? SC * o : SC * AL * expm1f(o);
    }
}

extern "C" void kernel_launch(void* const* d_in, const int* in_sizes, int n_in,
                              void* d_out, int out_size, void* d_ws, size_t ws_size,
                              hipStream_t stream) {
    const float* feat       = (const float*)d_in[0];
    const float* edge_feats = (const float*)d_in[1];
    const int*   src        = (const int*)d_in[2];
    const int*   dst        = (const int*)d_in[3];
    const float* weight     = (const float*)d_in[4];
    const float* bias       = (const float*)d_in[5];
    float* out = (float*)d_out;

    // ws layout: csr_pack(12.8MB) | deg_i | cursor | off(+1) | bsum | boff
    unsigned long long* csr_pack = (unsigned long long*)d_ws;
    unsigned* deg_i  = (unsigned*)(csr_pack + N_EDGES);
    unsigned* cursor = deg_i + N_NODES;
    unsigned* off    = cursor + N_NODES;            // N_NODES + 1
    unsigned* bsum   = off + N_NODES + 1;
    unsigned* boff   = bsum + NBLK;

    hipMemsetAsync(deg_i, 0, N_NODES * sizeof(unsigned), stream);

    hist_kernel<<<dim3((N_EDGES + 255) / 256), dim3(256), 0, stream>>>(dst, deg_i);
    scanA<<<dim3(NBLK), dim3(SCAN_B), 0, stream>>>(deg_i, bsum);
    scanB<<<dim3(1), dim3(128), 0, stream>>>(bsum, boff);
    scanC<<<dim3(NBLK), dim3(SCAN_B), 0, stream>>>(deg_i, boff, off, cursor);
    fill_kernel<<<dim3((N_EDGES + 255) / 256), dim3(256), 0, stream>>>(
        src, dst, cursor, csr_pack);
    gather_gemm<<<dim3(4096), dim3(256), 0, stream>>>(
        feat, edge_feats, csr_pack, off, weight, bias, out);
}

// Round 5
// 389.438 us; speedup vs baseline: 1.9492x; 1.3589x over previous
//
#include <hip/hip_runtime.h>
#include <hip/hip_bf16.h>
#include <math.h>

#define N_NODES 100000
#define N_EDGES 1600000
#define OUT_F   64
#define SCAN_B  1024
#define NBLK    ((N_NODES + SCAN_B - 1) / SCAN_B)   // 98

// ---------------------------------------------------------------------------
// G = feat @ W_h (weight rows 16..79), stored bf16 (12.8 MB).
// Wave per node: lane = out feature, feat row staged per-wave in LDS.
// ---------------------------------------------------------------------------
__global__ __launch_bounds__(256) void g_gemm(
    const float* __restrict__ feat, const float* __restrict__ weight,
    __hip_bfloat16* __restrict__ G)
{
    __shared__ float Wh[64 * 64];   // 16 KB
    __shared__ float fr[4][64];
    int tid = threadIdx.x;
    for (int i = tid; i < 64 * 64; i += 256) Wh[i] = weight[16 * 64 + i];
    __syncthreads();
    int wv = tid >> 6, ln = tid & 63;
    for (int n = blockIdx.x * 4 + wv; n < N_NODES; n += gridDim.x * 4) {
        fr[wv][ln] = feat[(size_t)n * 64 + ln];
        // same-wave LDS write->read ordered via lgkmcnt (validated R1-R3)
        float a0 = 0.f, a1 = 0.f;
        #pragma unroll
        for (int k = 0; k < 64; k += 2) {
            a0 = fmaf(fr[wv][k],     Wh[k * 64 + ln],       a0);
            a1 = fmaf(fr[wv][k + 1], Wh[(k + 1) * 64 + ln], a1);
        }
        G[(size_t)n * 64 + ln] = __float2bfloat16(a0 + a1);
    }
}

// ---------------------------------------------------------------------------
// CSR build 1: histogram + per-edge position (the ONLY atomic pass now).
// pos stored u16 (max degree << 65536).
// ---------------------------------------------------------------------------
__global__ __launch_bounds__(256) void hist_pos(
    const int* __restrict__ dst, unsigned* __restrict__ deg_i,
    unsigned short* __restrict__ pos)
{
    int e = blockIdx.x * 256 + threadIdx.x;
    if (e < N_EDGES) pos[e] = (unsigned short)atomicAdd(&deg_i[dst[e]], 1u);
}

// ---------------------------------------------------------------------------
// CSR build 2: hierarchical exclusive scan (R3-validated).
// ---------------------------------------------------------------------------
__global__ __launch_bounds__(SCAN_B) void scanA(
    const unsigned* __restrict__ deg_i, unsigned* __restrict__ bsum)
{
    __shared__ unsigned ws[16];
    int i = blockIdx.x * SCAN_B + threadIdx.x;
    unsigned v = (i < N_NODES) ? deg_i[i] : 0u;
    #pragma unroll
    for (int o = 32; o; o >>= 1) v += __shfl_down(v, o);
    if ((threadIdx.x & 63) == 0) ws[threadIdx.x >> 6] = v;
    __syncthreads();
    if (threadIdx.x < 16) {
        unsigned t = ws[threadIdx.x];
        #pragma unroll
        for (int o = 8; o; o >>= 1) t += __shfl_down(t, o);
        if (threadIdx.x == 0) bsum[blockIdx.x] = t;
    }
}

__global__ __launch_bounds__(128) void scanB(
    const unsigned* __restrict__ bsum, unsigned* __restrict__ boff)
{
    __shared__ unsigned s[128];
    int t = threadIdx.x;
    unsigned v = (t < NBLK) ? bsum[t] : 0u;
    s[t] = v; __syncthreads();
    #pragma unroll
    for (int o = 1; o < 128; o <<= 1) {
        unsigned u = (t >= o) ? s[t - o] : 0u;
        __syncthreads();
        s[t] += u;
        __syncthreads();
    }
    if (t < NBLK) boff[t] = s[t] - v;
}

__global__ __launch_bounds__(SCAN_B) void scanC(
    const unsigned* __restrict__ deg_i, const unsigned* __restrict__ boff,
    unsigned* __restrict__ off)
{
    __shared__ unsigned s[SCAN_B];
    int t = threadIdx.x;
    int i = blockIdx.x * SCAN_B + t;
    unsigned v = (i < N_NODES) ? deg_i[i] : 0u;
    s[t] = v; __syncthreads();
    #pragma unroll
    for (int o = 1; o < SCAN_B; o <<= 1) {
        unsigned u = (t >= o) ? s[t - o] : 0u;
        __syncthreads();
        s[t] += u;
        __syncthreads();
    }
    unsigned excl = s[t] - v + boff[blockIdx.x];
    if (i < N_NODES) off[i] = excl;
    if (i == N_NODES - 1) off[N_NODES] = excl + v;
}

// ---------------------------------------------------------------------------
// CSR build 3: fill WITHOUT atomics — slot = off[dst] + pos.
// ---------------------------------------------------------------------------
__global__ __launch_bounds__(256) void fill_kernel(
    const int* __restrict__ src, const int* __restrict__ dst,
    const unsigned short* __restrict__ pos, const unsigned* __restrict__ off,
    unsigned long long* __restrict__ csr_pack)
{
    int e = blockIdx.x * 256 + threadIdx.x;
    if (e >= N_EDGES) return;
    unsigned idx = off[dst[e]] + (unsigned)pos[e];
    csr_pack[idx] = (unsigned long long)(unsigned)src[e]
                  | ((unsigned long long)(unsigned)e << 32);
}

// ---------------------------------------------------------------------------
// Gather + full epilogue, ZERO LDS. One wave per node.
//   gh  = sum of G[src] rows (bf16 loads, lane = feature)
//   se  = sum of edge_feats rows (4 edges/group, shfl-reduced to lanes 0..15)
//   out = selu( norm2*(gh + se@W_e) + b ),  W_e column held in 16 VGPRs/lane,
//   se broadcast via 16 __shfl — no LDS dot, no 20 KB W tile.
// ---------------------------------------------------------------------------
__global__ __launch_bounds__(256) void gather_out(
    const __hip_bfloat16* __restrict__ G,
    const float* __restrict__ edge_feats,
    const unsigned long long* __restrict__ csr_pack,
    const unsigned* __restrict__ off,
    const float* __restrict__ weight,   // rows 0..15 = W_e
    const float* __restrict__ bias,
    float* __restrict__ out)
{
    int tid = threadIdx.x;
    int wv = tid >> 6, ln = tid & 63;
    int g = ln >> 4, f = ln & 15;

    float We[16];
    #pragma unroll
    for (int k = 0; k < 16; ++k) We[k] = weight[k * 64 + ln];
    float b = bias[ln];

    const float SC = 1.0507009873554805f;
    const float AL = 1.6732632423543772f;

    int n = blockIdx.x * 4 + wv;
    if (n >= N_NODES) return;

    unsigned start = off[n], end = off[n + 1];
    float norm2 = 1.0f / fmaxf((float)(end - start), 1.0f);

    float ah0 = 0.f, ah1 = 0.f, ah2 = 0.f, ah3 = 0.f;
    float ae0 = 0.f, ae1 = 0.f;

    for (unsigned base = start; base < end; base += 64u) {
        unsigned m = min(64u, end - base);
        unsigned lo = 0u, hi = 0u;
        if ((unsigned)ln < m) {
            unsigned long long pk = csr_pack[base + (unsigned)ln];
            lo = (unsigned)pk;
            hi = (unsigned)(pk >> 32);
        }
        unsigned i = 0;
        for (; i + 8u <= m; i += 8u) {
            unsigned s0 = __shfl(lo, (int)i);
            unsigned s1 = __shfl(lo, (int)i + 1);
            unsigned s2 = __shfl(lo, (int)i + 2);
            unsigned s3 = __shfl(lo, (int)i + 3);
            unsigned s4 = __shfl(lo, (int)i + 4);
            unsigned s5 = __shfl(lo, (int)i + 5);
            unsigned s6 = __shfl(lo, (int)i + 6);
            unsigned s7 = __shfl(lo, (int)i + 7);
            unsigned e0 = __shfl(hi, (int)i + g);
            unsigned e1 = __shfl(hi, (int)i + 4 + g);
            float ef0 = edge_feats[(size_t)e0 * 16u + (unsigned)f];
            float ef1 = edge_feats[(size_t)e1 * 16u + (unsigned)f];
            float h0 = __bfloat162float(G[(size_t)s0 * 64u + (unsigned)ln]);
            float h1 = __bfloat162float(G[(size_t)s1 * 64u + (unsigned)ln]);
            float h2 = __bfloat162float(G[(size_t)s2 * 64u + (unsigned)ln]);
            float h3 = __bfloat162float(G[(size_t)s3 * 64u + (unsigned)ln]);
            float h4 = __bfloat162float(G[(size_t)s4 * 64u + (unsigned)ln]);
            float h5 = __bfloat162float(G[(size_t)s5 * 64u + (unsigned)ln]);
            float h6 = __bfloat162float(G[(size_t)s6 * 64u + (unsigned)ln]);
            float h7 = __bfloat162float(G[(size_t)s7 * 64u + (unsigned)ln]);
            ae0 += ef0; ae1 += ef1;
            ah0 += h0; ah1 += h1; ah2 += h2; ah3 += h3;
            ah0 += h4; ah1 += h5; ah2 += h6; ah3 += h7;
        }
        for (; i + 4u <= m; i += 4u) {
            unsigned s0 = __shfl(lo, (int)i);
            unsigned s1 = __shfl(lo, (int)i + 1);
            unsigned s2 = __shfl(lo, (int)i + 2);
            unsigned s3 = __shfl(lo, (int)i + 3);
            unsigned e0 = __shfl(hi, (int)i + g);
            ae0 += edge_feats[(size_t)e0 * 16u + (unsigned)f];
            ah0 += __bfloat162float(G[(size_t)s0 * 64u + (unsigned)ln]);
            ah1 += __bfloat162float(G[(size_t)s1 * 64u + (unsigned)ln]);
            ah2 += __bfloat162float(G[(size_t)s2 * 64u + (unsigned)ln]);
            ah3 += __bfloat162float(G[(size_t)s3 * 64u + (unsigned)ln]);
        }
        for (; i < m; ++i) {
            unsigned si = __shfl(lo, (int)i);
            unsigned ei = __shfl(hi, (int)i);
            ah0 += __bfloat162float(G[(size_t)si * 64u + (unsigned)ln]);
            if (ln < 16) ae0 += edge_feats[(size_t)ei * 16u + (unsigned)ln];
        }
    }
    float gh = (ah0 + ah1) + (ah2 + ah3);
    float ae = ae0 + ae1;
    ae += __shfl_down(ae, 32);   // lanes 0..15 end up holding se[feature]
    ae += __shfl_down(ae, 16);

    float acc = gh;
    #pragma unroll
    for (int k = 0; k < 16; ++k)
        acc = fmaf(__shfl(ae, k), We[k], acc);

    float o = acc * norm2 + b;
    out[(size_t)n * 64u + ln] = (o > 0.f) ? SC * o : SC * AL * expm1f(o);
}

extern "C" void kernel_launch(void* const* d_in, const int* in_sizes, int n_in,
                              void* d_out, int out_size, void* d_ws, size_t ws_size,
                              hipStream_t stream) {
    const float* feat       = (const float*)d_in[0];
    const float* edge_feats = (const float*)d_in[1];
    const int*   src        = (const int*)d_in[2];
    const int*   dst        = (const int*)d_in[3];
    const float* weight     = (const float*)d_in[4];
    const float* bias       = (const float*)d_in[5];
    float* out = (float*)d_out;

    // ws: csr_pack 12.8MB | G 12.8MB | pos 3.2MB | deg_i .4 | off .4 | bsum/boff
    unsigned long long* csr_pack = (unsigned long long*)d_ws;
    __hip_bfloat16* G   = (__hip_bfloat16*)(csr_pack + N_EDGES);
    unsigned short* pos = (unsigned short*)(G + (size_t)N_NODES * 64);
    unsigned* deg_i = (unsigned*)(pos + N_EDGES);
    unsigned* off   = deg_i + N_NODES;            // N_NODES + 1
    unsigned* bsum  = off + N_NODES + 1;          // NBLK
    unsigned* boff  = bsum + NBLK;                // NBLK

    hipMemsetAsync(deg_i, 0, N_NODES * sizeof(unsigned), stream);

    g_gemm<<<dim3(2048), dim3(256), 0, stream>>>(feat, weight, G);
    hist_pos<<<dim3((N_EDGES + 255) / 256), dim3(256), 0, stream>>>(dst, deg_i, pos);
    scanA<<<dim3(NBLK), dim3(SCAN_B), 0, stream>>>(deg_i, bsum);
    scanB<<<dim3(1), dim3(128), 0, stream>>>(bsum, boff);
    scanC<<<dim3(NBLK), dim3(SCAN_B), 0, stream>>>(deg_i, boff, off);
    fill_kernel<<<dim3((N_EDGES + 255) / 256), dim3(256), 0, stream>>>(
        src, dst, pos, off, csr_pack);
    gather_out<<<dim3((N_NODES + 3) / 4), dim3(256), 0, stream>>>(
        G, edge_feats, csr_pack, off, weight, bias, out);
}

// Round 6
// 381.806 us; speedup vs baseline: 1.9881x; 1.0200x over previous
//
#include <hip/hip_runtime.h>
#include <hip/hip_bf16.h>
#include <math.h>

#define N_NODES 100000
#define N_EDGES 1600000
#define OUT_F   64
#define SCAN_B  1024
#define NBLK    ((N_NODES + SCAN_B - 1) / SCAN_B)   // 98

// ---------------------------------------------------------------------------
// prep: (a) zero deg_i (replaces host memset node), (b) G = feat @ W_h, bf16.
// Both node-parallel; visibility to later dispatches via stream ordering.
// ---------------------------------------------------------------------------
__global__ __launch_bounds__(256) void prep(
    const float* __restrict__ feat, const float* __restrict__ weight,
    __hip_bfloat16* __restrict__ G, unsigned* __restrict__ deg_i)
{
    __shared__ float Wh[64 * 64];   // 16 KB
    __shared__ float fr[4][64];
    int tid = threadIdx.x;
    for (int i = blockIdx.x * 256 + tid; i < N_NODES; i += gridDim.x * 256)
        deg_i[i] = 0u;
    for (int i = tid; i < 64 * 64; i += 256) Wh[i] = weight[16 * 64 + i];
    __syncthreads();
    int wv = tid >> 6, ln = tid & 63;
    for (int n = blockIdx.x * 4 + wv; n < N_NODES; n += gridDim.x * 4) {
        fr[wv][ln] = feat[(size_t)n * 64 + ln];
        // same-wave LDS write->read ordered via lgkmcnt (validated R1-R5)
        float a0 = 0.f, a1 = 0.f;
        #pragma unroll
        for (int k = 0; k < 64; k += 2) {
            a0 = fmaf(fr[wv][k],     Wh[k * 64 + ln],       a0);
            a1 = fmaf(fr[wv][k + 1], Wh[(k + 1) * 64 + ln], a1);
        }
        G[(size_t)n * 64 + ln] = __float2bfloat16(a0 + a1);
    }
}

// ---------------------------------------------------------------------------
// CSR build 1: histogram + per-edge position (only atomic pass). pos u16.
// ---------------------------------------------------------------------------
__global__ __launch_bounds__(256) void hist_pos(
    const int* __restrict__ dst, unsigned* __restrict__ deg_i,
    unsigned short* __restrict__ pos)
{
    int e = blockIdx.x * 256 + threadIdx.x;
    if (e < N_EDGES) pos[e] = (unsigned short)atomicAdd(&deg_i[dst[e]], 1u);
}

// ---------------------------------------------------------------------------
// CSR build 2: hierarchical exclusive scan (R3/R5-validated).
// ---------------------------------------------------------------------------
__global__ __launch_bounds__(SCAN_B) void scanA(
    const unsigned* __restrict__ deg_i, unsigned* __restrict__ bsum)
{
    __shared__ unsigned ws[16];
    int i = blockIdx.x * SCAN_B + threadIdx.x;
    unsigned v = (i < N_NODES) ? deg_i[i] : 0u;
    #pragma unroll
    for (int o = 32; o; o >>= 1) v += __shfl_down(v, o);
    if ((threadIdx.x & 63) == 0) ws[threadIdx.x >> 6] = v;
    __syncthreads();
    if (threadIdx.x < 16) {
        unsigned t = ws[threadIdx.x];
        #pragma unroll
        for (int o = 8; o; o >>= 1) t += __shfl_down(t, o);
        if (threadIdx.x == 0) bsum[blockIdx.x] = t;
    }
}

__global__ __launch_bounds__(128) void scanB(
    const unsigned* __restrict__ bsum, unsigned* __restrict__ boff)
{
    __shared__ unsigned s[128];
    int t = threadIdx.x;
    unsigned v = (t < NBLK) ? bsum[t] : 0u;
    s[t] = v; __syncthreads();
    #pragma unroll
    for (int o = 1; o < 128; o <<= 1) {
        unsigned u = (t >= o) ? s[t - o] : 0u;
        __syncthreads();
        s[t] += u;
        __syncthreads();
    }
    if (t < NBLK) boff[t] = s[t] - v;
}

__global__ __launch_bounds__(SCAN_B) void scanC(
    const unsigned* __restrict__ deg_i, const unsigned* __restrict__ boff,
    unsigned* __restrict__ off)
{
    __shared__ unsigned s[SCAN_B];
    int t = threadIdx.x;
    int i = blockIdx.x * SCAN_B + t;
    unsigned v = (i < N_NODES) ? deg_i[i] : 0u;
    s[t] = v; __syncthreads();
    #pragma unroll
    for (int o = 1; o < SCAN_B; o <<= 1) {
        unsigned u = (t >= o) ? s[t - o] : 0u;
        __syncthreads();
        s[t] += u;
        __syncthreads();
    }
    unsigned excl = s[t] - v + boff[blockIdx.x];
    if (i < N_NODES) off[i] = excl;
    if (i == N_NODES - 1) off[N_NODES] = excl + v;
}

// ---------------------------------------------------------------------------
// CSR build 3: atomic-free fill — slot = off[dst] + pos.
// ---------------------------------------------------------------------------
__global__ __launch_bounds__(256) void fill_kernel(
    const int* __restrict__ src, const int* __restrict__ dst,
    const unsigned short* __restrict__ pos, const unsigned* __restrict__ off,
    unsigned long long* __restrict__ csr_pack)
{
    int e = blockIdx.x * 256 + threadIdx.x;
    if (e >= N_EDGES) return;
    unsigned idx = off[dst[e]] + (unsigned)pos[e];
    csr_pack[idx] = (unsigned long long)(unsigned)src[e]
                  | ((unsigned long long)(unsigned)e << 32);
}

// ---------------------------------------------------------------------------
// Gather + epilogue, zero LDS, vectorized lane geometry. One wave per node.
//  G rows  : ushort4 (4 bf16)/lane, 16 lanes/row -> 4 rows PER LOAD INSTR;
//            row index via one per-lane-indexed __shfl (ds_bpermute).
//  EF rows : float4/lane, 4 lanes/row -> 16 rows PER LOAD INSTR.
//  Packed per-lane accumulators; ONE butterfly reduction per node at the end.
//  Memory instrs per 16-edge node: 21 -> 6.
// ---------------------------------------------------------------------------
__global__ __launch_bounds__(256) void gather_out(
    const __hip_bfloat16* __restrict__ G,
    const float* __restrict__ edge_feats,
    const unsigned long long* __restrict__ csr_pack,
    const unsigned* __restrict__ off,
    const float* __restrict__ weight,   // rows 0..15 = W_e
    const float* __restrict__ bias,
    float* __restrict__ out)
{
    int tid = threadIdx.x;
    int wv = tid >> 6, ln = tid & 63;

    float We[16];
    #pragma unroll
    for (int k = 0; k < 16; ++k) We[k] = weight[k * 64 + ln];
    float b = bias[ln];

    const float SC = 1.0507009873554805f;
    const float AL = 1.6732632423543772f;

    int n = blockIdx.x * 4 + wv;
    if (n >= N_NODES) return;

    unsigned start = off[n], end = off[n + 1];
    float norm2 = 1.0f / fmaxf((float)(end - start), 1.0f);

    const int gq = ln >> 4;   // G row-group 0..3   (lane covers feat block ln&15)
    const int eq = ln >> 2;   // EF row-group 0..15 (lane covers feat block ln&3)

    float gh4[4] = {0.f, 0.f, 0.f, 0.f};   // G feats 4*(ln&15)+c, summed rows
    float ae4[4] = {0.f, 0.f, 0.f, 0.f};   // EF feats 4*(ln&3)+c, summed rows

    const ushort4* __restrict__ Gv = (const ushort4*)G;   // row n = Gv[n*16 + blk]

    for (unsigned base = start; base < end; base += 64u) {
        unsigned m = min(64u, end - base);
        unsigned lo = 0u, hi = 0u;
        if ((unsigned)ln < m) {
            unsigned long long pk = csr_pack[base + (unsigned)ln];
            lo = (unsigned)pk;
            hi = (unsigned)(pk >> 32);
        }

        // ---- G: 8 edges per iteration = 2 independent 8B loads ----
        for (unsigned i = 0; i < m; i += 8u) {
            unsigned i0 = i + (unsigned)gq, i1 = i0 + 4u;
            unsigned s0 = __shfl(lo, (int)min(i0, m - 1u));
            unsigned s1 = __shfl(lo, (int)min(i1, m - 1u));
            ushort4 q0 = {0,0,0,0}, q1 = {0,0,0,0};
            if (i0 < m) q0 = Gv[(size_t)s0 * 16u + (unsigned)(ln & 15)];
            if (i1 < m) q1 = Gv[(size_t)s1 * 16u + (unsigned)(ln & 15)];
            gh4[0] += __uint_as_float((unsigned)q0.x << 16) + __uint_as_float((unsigned)q1.x << 16);
            gh4[1] += __uint_as_float((unsigned)q0.y << 16) + __uint_as_float((unsigned)q1.y << 16);
            gh4[2] += __uint_as_float((unsigned)q0.z << 16) + __uint_as_float((unsigned)q1.z << 16);
            gh4[3] += __uint_as_float((unsigned)q0.w << 16) + __uint_as_float((unsigned)q1.w << 16);
        }

        // ---- EF: 16 edges per load instr ----
        for (unsigned i = 0; i < m; i += 16u) {
            unsigned ie = i + (unsigned)eq;
            unsigned e0 = __shfl(hi, (int)min(ie, m - 1u));
            if (ie < m) {
                float4 v = *(const float4*)(edge_feats + (size_t)e0 * 16u + (unsigned)(ln & 3) * 4u);
                ae4[0] += v.x; ae4[1] += v.y; ae4[2] += v.z; ae4[3] += v.w;
            }
        }
    }

    // ---- one-shot cross-lane reductions ----
    #pragma unroll
    for (int c = 0; c < 4; ++c) {
        gh4[c] += __shfl_xor(gh4[c], 16);
        gh4[c] += __shfl_xor(gh4[c], 32);
        ae4[c] += __shfl_xor(ae4[c], 4);
        ae4[c] += __shfl_xor(ae4[c], 8);
        ae4[c] += __shfl_xor(ae4[c], 16);
        ae4[c] += __shfl_xor(ae4[c], 32);
    }
    // gh4[c] now valid on all lanes: feats 4*(ln&15)+c. Repack to lane=feature:
    int srcl = ln >> 2;
    float r0 = __shfl(gh4[0], srcl);
    float r1 = __shfl(gh4[1], srcl);
    float r2 = __shfl(gh4[2], srcl);
    float r3 = __shfl(gh4[3], srcl);
    int c = ln & 3;
    float gh = (c & 2) ? ((c & 1) ? r3 : r2) : ((c & 1) ? r1 : r0);

    // se[k] = comp (k&3) of ae4 at lane (k>>2); all compile-time in unroll
    float acc = gh;
    #pragma unroll
    for (int k = 0; k < 16; ++k)
        acc = fmaf(__shfl(ae4[k & 3], k >> 2), We[k], acc);

    float o = acc * norm2 + b;
    out[(size_t)n * 64u + ln] = (o > 0.f) ? SC * o : SC * AL * expm1f(o);
}

extern "C" void kernel_launch(void* const* d_in, const int* in_sizes, int n_in,
                              void* d_out, int out_size, void* d_ws, size_t ws_size,
                              hipStream_t stream) {
    const float* feat       = (const float*)d_in[0];
    const float* edge_feats = (const float*)d_in[1];
    const int*   src        = (const int*)d_in[2];
    const int*   dst        = (const int*)d_in[3];
    const float* weight     = (const float*)d_in[4];
    const float* bias       = (const float*)d_in[5];
    float* out = (float*)d_out;

    // ws: csr_pack 12.8MB | G 12.8MB | pos 3.2MB | deg_i | off(+1) | bsum | boff
    unsigned long long* csr_pack = (unsigned long long*)d_ws;
    __hip_bfloat16* G   = (__hip_bfloat16*)(csr_pack + N_EDGES);
    unsigned short* pos = (unsigned short*)(G + (size_t)N_NODES * 64);
    unsigned* deg_i = (unsigned*)(pos + N_EDGES);
    unsigned* off   = deg_i + N_NODES;            // N_NODES + 1
    unsigned* bsum  = off + N_NODES + 1;          // NBLK
    unsigned* boff  = bsum + NBLK;                // NBLK

    prep<<<dim3(2048), dim3(256), 0, stream>>>(feat, weight, G, deg_i);
    hist_pos<<<dim3((N_EDGES + 255) / 256), dim3(256), 0, stream>>>(dst, deg_i, pos);
    scanA<<<dim3(NBLK), dim3(SCAN_B), 0, stream>>>(deg_i, bsum);
    scanB<<<dim3(1), dim3(128), 0, stream>>>(bsum, boff);
    scanC<<<dim3(NBLK), dim3(SCAN_B), 0, stream>>>(deg_i, boff, off);
    fill_kernel<<<dim3((N_EDGES + 255) / 256), dim3(256), 0, stream>>>(
        src, dst, pos, off, csr_pack);
    gather_out<<<dim3((N_NODES + 3) / 4), dim3(256), 0, stream>>>(
        G, edge_feats, csr_pack, off, weight, bias, out);
}